// Round 3
// baseline (240.925 us; speedup 1.0000x reference)
//
#include <hip/hip_runtime.h>
#include <stdint.h>

// Problem constants (fixed by the reference).
#define VOCAB_P1 100001
#define EMB_DIM  128
#define BATCH    256
#define NNZ_Q    2048
#define NNZ_D    262144

#define NPAD 112   // hidden dim 100 padded to 7 MFMA tiles of 16
#define ROWP 136   // w1t LDS row stride in shorts: 128 + 8 (16B-aligned, odd 16B-unit count)
#define NGRP 6251  // ceil(100001 / 16) row-groups for the MLP

#define WS_ZERO_FLOATS (100352 + 256)   // rowsum + colsum region of d_ws

typedef __attribute__((ext_vector_type(8))) short  short8;   // 8 bf16 = 4 VGPRs
typedef __attribute__((ext_vector_type(4))) float  float4v;  // MFMA acc

__device__ __forceinline__ unsigned short f2bf(float f) {
    union { float f; unsigned u; } v; v.f = f;
    unsigned u = v.u;
    u += 0x7fffu + ((u >> 16) & 1u);     // RNE float -> bf16
    return (unsigned short)(u >> 16);
}

__device__ __forceinline__ short8 cvt8(float4 a, float4 b) {
    short8 r;
    r[0] = (short)f2bf(a.x); r[1] = (short)f2bf(a.y);
    r[2] = (short)f2bf(a.z); r[3] = (short)f2bf(a.w);
    r[4] = (short)f2bf(b.x); r[5] = (short)f2bf(b.y);
    r[6] = (short)f2bf(b.z); r[7] = (short)f2bf(b.w);
    return r;
}

// Exact-size zeroing: d_out (n4a float4s) + the small ws stats region (n4b).
// Replaces runtime fillBuffer, which was observed writing 4x the bytes.
__global__ __launch_bounds__(256) void zero_kernel(
    float4* __restrict__ a, int n4a, float4* __restrict__ b, int n4b)
{
    const float4 z = {0.f, 0.f, 0.f, 0.f};
    int stride = gridDim.x * 256;
    for (int i = blockIdx.x * 256 + threadIdx.x; i < n4a; i += stride)
        a[i] = z;
    for (int i = blockIdx.x * 256 + threadIdx.x; i < n4b; i += stride)
        b[i] = z;
}

// Per-UNIQUE-vocab-row MLP: tdv[r] = relu(relu(emb[r] @ W1 + b1) @ W2 + b2).
// emb is STREAMED coalesced (no gather); A-fragments come straight from
// global (16B/lane), B (W1^T bf16) staged once per block in LDS.
__global__ __launch_bounds__(256) void mlp_tdv_kernel(
    const float* __restrict__ emb, const float* __restrict__ W1,
    const float* __restrict__ b1, const float* __restrict__ W2,
    const float* __restrict__ b2, float* __restrict__ tdvtab)
{
    __shared__ __align__(16) short w1t[NPAD * ROWP];   // 30.5 KB
    __shared__ float b1s[NPAD];
    __shared__ float w2s[NPAD];

    const int tid = threadIdx.x;

    int* w1i = (int*)w1t;
    for (int i = tid; i < NPAD * ROWP / 2; i += 256) w1i[i] = 0;
    __syncthreads();
    for (int f = tid; f < EMB_DIM * 100; f += 256) {
        int k = f / 100, j = f - k * 100;
        w1t[j * ROWP + k] = (short)f2bf(W1[f]);
    }
    if (tid < NPAD) {
        b1s[tid] = (tid < 100) ? b1[tid] : 0.f;
        w2s[tid] = (tid < 100) ? W2[tid] : 0.f;
    }
    __syncthreads();

    const int lane = tid & 63;
    const int w    = tid >> 6;
    const int col  = lane & 15;
    const int quad = lane >> 4;
    const float b2v = b2[0];
    const int nw = gridDim.x * 4;

    for (int grp = blockIdx.x * 4 + w; grp < NGRP; grp += nw) {
        int r  = grp * 16 + col;
        int rr = (r <= VOCAB_P1 - 1) ? r : (VOCAB_P1 - 1);   // clamp OOB reads
        const float* rp = emb + (size_t)rr * EMB_DIM + quad * 8;
        // A layout: A[m=lane&15][k=quad*8+j], fragment f covers k0=f*32.
        float4 u0 = *(const float4*)(rp);
        float4 u1 = *(const float4*)(rp + 4);
        float4 u2 = *(const float4*)(rp + 32);
        float4 u3 = *(const float4*)(rp + 36);
        float4 u4 = *(const float4*)(rp + 64);
        float4 u5 = *(const float4*)(rp + 68);
        float4 u6 = *(const float4*)(rp + 96);
        float4 u7 = *(const float4*)(rp + 100);
        short8 a0 = cvt8(u0, u1), a1 = cvt8(u2, u3);
        short8 a2 = cvt8(u4, u5), a3 = cvt8(u6, u7);

        float s0 = 0.f, s1 = 0.f, s2 = 0.f, s3 = 0.f;
        for (int jt = 0; jt < 7; ++jt) {
            const short* bp = &w1t[(jt * 16 + col) * ROWP + quad * 8];
            short8 bv0 = *(const short8*)(bp);
            short8 bv1 = *(const short8*)(bp + 32);
            short8 bv2 = *(const short8*)(bp + 64);
            short8 bv3 = *(const short8*)(bp + 96);

            float4v acc = {0.f, 0.f, 0.f, 0.f};
            acc = __builtin_amdgcn_mfma_f32_16x16x32_bf16(a0, bv0, acc, 0, 0, 0);
            acc = __builtin_amdgcn_mfma_f32_16x16x32_bf16(a1, bv1, acc, 0, 0, 0);
            acc = __builtin_amdgcn_mfma_f32_16x16x32_bf16(a2, bv2, acc, 0, 0, 0);
            acc = __builtin_amdgcn_mfma_f32_16x16x32_bf16(a3, bv3, acc, 0, 0, 0);

            // D layout: row = quad*4 + reg, col(j) = lane&15
            float b1v = b1s[jt * 16 + col];
            float w2v = w2s[jt * 16 + col];
            float h;
            h = acc[0] + b1v; h = h > 0.f ? h : 0.f; s0 += h * w2v;
            h = acc[1] + b1v; h = h > 0.f ? h : 0.f; s1 += h * w2v;
            h = acc[2] + b1v; h = h > 0.f ? h : 0.f; s2 += h * w2v;
            h = acc[3] + b1v; h = h > 0.f ? h : 0.f; s3 += h * w2v;
        }
        for (int m = 1; m < 16; m <<= 1) {
            s0 += __shfl_xor(s0, m, 64);
            s1 += __shfl_xor(s1, m, 64);
            s2 += __shfl_xor(s2, m, 64);
            s3 += __shfl_xor(s3, m, 64);
        }
        if (col < 4) {
            float sv = (col == 0) ? s0 : (col == 1) ? s1 : (col == 2) ? s2 : s3;
            int row = grp * 16 + quad * 4 + col;
            if (row < VOCAB_P1) {
                float tdv = sv + b2v;
                tdvtab[row] = tdv > 0.f ? tdv : 0.f;
            }
        }
    }
}

// Per-entry scatter, 1 entry/thread (1024 blocks -> 16 waves/CU for latency
// hiding). colsum aggregated per-block in LDS to cut same-address contention.
__global__ __launch_bounds__(256) void scatter_kernel(
    const int* __restrict__ d_rows, const int* __restrict__ d_cols,
    const float* __restrict__ d_freqs, const float* __restrict__ tdvtab,
    float* __restrict__ dmat, float* __restrict__ rowsum,
    float* __restrict__ colsum)
{
    __shared__ float cs[BATCH];
    const int tid = threadIdx.x;
    cs[tid] = 0.f;
    __syncthreads();

    int e = blockIdx.x * 256 + tid;
    int   r = d_rows[e];
    int   c = d_cols[e];
    float f = d_freqs[e];
    float ft = tdvtab[r] * f;

    atomicAdd(&dmat[(size_t)r * BATCH + c], ft);
    atomicAdd(&rowsum[r], ft);
    atomicAdd(&cs[c], ft);

    __syncthreads();
    atomicAdd(&colsum[tid], cs[tid]);
}

// rel[b] = sum_e q_vals[e] * dir_d[q_rows[e], q_cols[e]] — dir_d evaluated
// at the 2048 q positions only. Each block redundantly reduces total(=sum colsum).
__global__ __launch_bounds__(256) void rel_kernel(
    const int* __restrict__ q_rows, const int* __restrict__ q_cols,
    const float* __restrict__ q_vals, const float* __restrict__ dmat,
    const float* __restrict__ rowsum, const float* __restrict__ colsum,
    const float* __restrict__ mu_p, float* __restrict__ rel)
{
    __shared__ float csh[BATCH];
    __shared__ float red[BATCH];
    const int tid = threadIdx.x;
    float c = colsum[tid];
    csh[tid] = c;
    red[tid] = c;
    __syncthreads();
    for (int s = 128; s > 0; s >>= 1) {
        if (tid < s) red[tid] += red[tid + s];
        __syncthreads();
    }
    float tot = red[0];
    float mu  = mu_p[0];

    int e = blockIdx.x * 256 + tid;              // 8 blocks x 256 = 2048
    int v = q_rows[e], b = q_cols[e];
    float dval = dmat[(size_t)v * BATCH + b];
    float cf   = rowsum[v] / tot;
    float dir  = log1pf(dval / (1.f + mu * cf)) + logf(mu / (csh[b] + mu));
    atomicAdd(&rel[b], q_vals[e] * dir);
}

extern "C" void kernel_launch(void* const* d_in, const int* in_sizes, int n_in,
                              void* d_out, int out_size, void* d_ws, size_t ws_size,
                              hipStream_t stream)
{
    const int*   q_rows  = (const int*)d_in[0];
    const int*   q_cols  = (const int*)d_in[1];
    const float* q_vals  = (const float*)d_in[2];
    const int*   d_rows  = (const int*)d_in[3];
    const int*   d_cols  = (const int*)d_in[4];
    const float* d_freqs = (const float*)d_in[5];
    const float* emb     = (const float*)d_in[6];
    const float* W1      = (const float*)d_in[7];
    const float* b1      = (const float*)d_in[8];
    const float* W2      = (const float*)d_in[9];
    const float* b2      = (const float*)d_in[10];
    const float* mu      = (const float*)d_in[11];

    float* rel  = (float*)d_out;          // output 0: rel [256]
    float* dmat = rel + BATCH;            // output 1: d [100001, 256]

    float* rowsum = (float*)d_ws;         // [100352]
    float* colsum = rowsum + 100352;      // [256]
    float* tdvtab = colsum + 256;         // [100001]

    // Exact-size zero of d_out + ws stats (out_size = 25,600,512 -> /4 exact).
    zero_kernel<<<2048, 256, 0, stream>>>(
        (float4*)d_out, out_size / 4, (float4*)d_ws, WS_ZERO_FLOATS / 4);

    mlp_tdv_kernel<<<1024, 256, 0, stream>>>(emb, W1, b1, W2, b2, tdvtab);
    scatter_kernel<<<NNZ_D / 256, 256, 0, stream>>>(
        d_rows, d_cols, d_freqs, tdvtab, dmat, rowsum, colsum);
    rel_kernel<<<NNZ_Q / 256, 256, 0, stream>>>(
        q_rows, q_cols, q_vals, dmat, rowsum, colsum, mu, rel);
}

// Round 4
// 204.795 us; speedup vs baseline: 1.1764x; 1.1764x over previous
//
#include <hip/hip_runtime.h>
#include <stdint.h>

// Problem constants (fixed by the reference).
#define VOCAB_P1 100001
#define EMB_DIM  128
#define BATCH    256
#define NNZ_Q    2048
#define NNZ_D    262144

#define NPAD 112        // hidden dim 100 padded to 7 MFMA tiles of 16
#define ROWP 136        // w1t LDS row stride in shorts (128 + 8 pad)
#define NGRP 6251       // ceil(100001 / 16) row-groups
#define ZBLK 256        // zero-role blocks
#define MBLK 1024       // mlp-role blocks
#define OUT_F4 6400128  // out_size/4 = 25,600,512 floats / 4

typedef __attribute__((ext_vector_type(8))) short  short8;
typedef __attribute__((ext_vector_type(4))) float  float4v;

__device__ __forceinline__ unsigned short f2bf(float f) {
    union { float f; unsigned u; } v; v.f = f;
    unsigned u = v.u;
    u += 0x7fffu + ((u >> 16) & 1u);     // RNE float -> bf16
    return (unsigned short)(u >> 16);
}

__device__ __forceinline__ short8 cvt8(float4 a, float4 b) {
    short8 r;
    r[0] = (short)f2bf(a.x); r[1] = (short)f2bf(a.y);
    r[2] = (short)f2bf(a.z); r[3] = (short)f2bf(a.w);
    r[4] = (short)f2bf(b.x); r[5] = (short)f2bf(b.y);
    r[6] = (short)f2bf(b.z); r[7] = (short)f2bf(b.w);
    return r;
}

// Block-role fused kernel:
//   blocks [0, ZBLK): zero d_out (rel + dmat) and the two colsum copies.
//   blocks [ZBLK, ZBLK+MBLK): per-unique-row MLP tdv table.
// Roles are independent; stream-ordered scatter sees both complete.
__global__ __launch_bounds__(256) void zero_mlp_kernel(
    float* __restrict__ d_out_f, float* __restrict__ colsum2,
    const float* __restrict__ emb, const float* __restrict__ W1,
    const float* __restrict__ b1, const float* __restrict__ W2,
    const float* __restrict__ b2, float* __restrict__ tdvtab)
{
    const int tid = threadIdx.x;

    if (blockIdx.x < ZBLK) {
        const float4 z = {0.f, 0.f, 0.f, 0.f};
        float4* dst = (float4*)d_out_f;
        int i0 = blockIdx.x * 256 + tid;
        for (int i = i0; i < OUT_F4; i += ZBLK * 256) dst[i] = z;
        if (i0 < 128) ((float4*)colsum2)[i0] = z;   // 2 x 256 floats
        return;
    }

    __shared__ __align__(16) short w1t[NPAD * ROWP];   // 30.5 KB
    __shared__ float b1s[NPAD];
    __shared__ float w2s[NPAD];

    int* w1i = (int*)w1t;
    for (int i = tid; i < NPAD * ROWP / 2; i += 256) w1i[i] = 0;
    __syncthreads();
    for (int f = tid; f < EMB_DIM * 100; f += 256) {
        int k = f / 100, j = f - k * 100;
        w1t[j * ROWP + k] = (short)f2bf(W1[f]);
    }
    if (tid < NPAD) {
        b1s[tid] = (tid < 100) ? b1[tid] : 0.f;
        w2s[tid] = (tid < 100) ? W2[tid] : 0.f;
    }
    __syncthreads();

    const int lane = tid & 63;
    const int w    = tid >> 6;
    const int col  = lane & 15;
    const int quad = lane >> 4;
    const float b2v = b2[0];
    const int bid  = blockIdx.x - ZBLK;

    for (int grp = bid * 4 + w; grp < NGRP; grp += MBLK * 4) {
        int r  = grp * 16 + col;
        int rr = (r <= VOCAB_P1 - 1) ? r : (VOCAB_P1 - 1);
        const float* rp = emb + (size_t)rr * EMB_DIM + quad * 8;
        // A layout: A[m=lane&15][k=quad*8+j]
        float4 u0 = *(const float4*)(rp);
        float4 u1 = *(const float4*)(rp + 4);
        float4 u2 = *(const float4*)(rp + 32);
        float4 u3 = *(const float4*)(rp + 36);
        float4 u4 = *(const float4*)(rp + 64);
        float4 u5 = *(const float4*)(rp + 68);
        float4 u6 = *(const float4*)(rp + 96);
        float4 u7 = *(const float4*)(rp + 100);
        short8 a0 = cvt8(u0, u1), a1 = cvt8(u2, u3);
        short8 a2 = cvt8(u4, u5), a3 = cvt8(u6, u7);

        float s0 = 0.f, s1 = 0.f, s2 = 0.f, s3 = 0.f;
        for (int jt = 0; jt < 7; ++jt) {
            const short* bp = &w1t[(jt * 16 + col) * ROWP + quad * 8];
            short8 bv0 = *(const short8*)(bp);
            short8 bv1 = *(const short8*)(bp + 32);
            short8 bv2 = *(const short8*)(bp + 64);
            short8 bv3 = *(const short8*)(bp + 96);

            float4v acc = {0.f, 0.f, 0.f, 0.f};
            acc = __builtin_amdgcn_mfma_f32_16x16x32_bf16(a0, bv0, acc, 0, 0, 0);
            acc = __builtin_amdgcn_mfma_f32_16x16x32_bf16(a1, bv1, acc, 0, 0, 0);
            acc = __builtin_amdgcn_mfma_f32_16x16x32_bf16(a2, bv2, acc, 0, 0, 0);
            acc = __builtin_amdgcn_mfma_f32_16x16x32_bf16(a3, bv3, acc, 0, 0, 0);

            // D layout: row = quad*4 + reg, col(j) = lane&15
            float b1v = b1s[jt * 16 + col];
            float w2v = w2s[jt * 16 + col];
            float h;
            h = acc[0] + b1v; h = h > 0.f ? h : 0.f; s0 += h * w2v;
            h = acc[1] + b1v; h = h > 0.f ? h : 0.f; s1 += h * w2v;
            h = acc[2] + b1v; h = h > 0.f ? h : 0.f; s2 += h * w2v;
            h = acc[3] + b1v; h = h > 0.f ? h : 0.f; s3 += h * w2v;
        }
        for (int m = 1; m < 16; m <<= 1) {
            s0 += __shfl_xor(s0, m, 64);
            s1 += __shfl_xor(s1, m, 64);
            s2 += __shfl_xor(s2, m, 64);
            s3 += __shfl_xor(s3, m, 64);
        }
        if (col < 4) {
            float sv = (col == 0) ? s0 : (col == 1) ? s1 : (col == 2) ? s2 : s3;
            int row = grp * 16 + quad * 4 + col;
            if (row < VOCAB_P1) {
                float tdv = sv + b2v;
                tdvtab[row] = tdv > 0.f ? tdv : 0.f;
            }
        }
    }
}

// Scatter: ft = tdv[row]*freq -> dmat atomics + LDS colsum. 512 blocks x
// 2 entries/thread (8 waves/CU). colsum flushed to 2 copies by block parity
// (halves per-address atomic chain depth); rel sums the copies.
__global__ __launch_bounds__(256) void scatter_kernel(
    const int* __restrict__ d_rows, const int* __restrict__ d_cols,
    const float* __restrict__ d_freqs, const float* __restrict__ tdvtab,
    float* __restrict__ dmat, float* __restrict__ colsum2)
{
    __shared__ float cs[BATCH];
    const int tid = threadIdx.x;
    cs[tid] = 0.f;
    __syncthreads();

    int g = blockIdx.x * 256 + tid;              // int2 index, 131072 total
    int2   r2 = ((const int2*)d_rows)[g];
    int2   c2 = ((const int2*)d_cols)[g];
    float2 f2 = ((const float2*)d_freqs)[g];

    float ft0 = tdvtab[r2.x] * f2.x;
    float ft1 = tdvtab[r2.y] * f2.y;

    atomicAdd(&dmat[(size_t)r2.x * BATCH + c2.x], ft0);
    atomicAdd(&dmat[(size_t)r2.y * BATCH + c2.y], ft1);
    atomicAdd(&cs[c2.x], ft0);
    atomicAdd(&cs[c2.y], ft1);

    __syncthreads();
    atomicAdd(&colsum2[(blockIdx.x & 1) * BATCH + tid], cs[tid]);
}

// One WAVE per q-entry: rowsum[v] = sum of dmat row v (1 float4/lane),
// total = sum of colsum (1 float4/lane), both shuffle-reduced in-wave.
__global__ __launch_bounds__(256) void rel_kernel(
    const int* __restrict__ q_rows, const int* __restrict__ q_cols,
    const float* __restrict__ q_vals, const float* __restrict__ dmat,
    const float* __restrict__ colsum2, const float* __restrict__ mu_p,
    float* __restrict__ rel)
{
    const int tid  = threadIdx.x;
    const int lane = tid & 63;
    const int e    = blockIdx.x * 4 + (tid >> 6);   // 512 blocks x 4 waves = 2048

    int v = q_rows[e], b = q_cols[e];
    float qv = q_vals[e];
    float mu = mu_p[0];

    float4 cv  = *(const float4*)(colsum2 + lane * 4);
    float4 cv2 = *(const float4*)(colsum2 + BATCH + lane * 4);
    float4 rv  = *(const float4*)(dmat + (size_t)v * BATCH + lane * 4);
    float tot_p = cv.x + cv.y + cv.z + cv.w + cv2.x + cv2.y + cv2.z + cv2.w;
    float row_p = rv.x + rv.y + rv.z + rv.w;
    for (int m = 1; m < 64; m <<= 1) {
        tot_p += __shfl_xor(tot_p, m, 64);
        row_p += __shfl_xor(row_p, m, 64);
    }

    if (lane == 0) {
        float csb  = colsum2[b] + colsum2[BATCH + b];
        float dval = dmat[(size_t)v * BATCH + b];
        float cf   = row_p / tot_p;
        float dir  = log1pf(dval / (1.f + mu * cf)) + logf(mu / (csb + mu));
        atomicAdd(&rel[b], qv * dir);
    }
}

extern "C" void kernel_launch(void* const* d_in, const int* in_sizes, int n_in,
                              void* d_out, int out_size, void* d_ws, size_t ws_size,
                              hipStream_t stream)
{
    const int*   q_rows  = (const int*)d_in[0];
    const int*   q_cols  = (const int*)d_in[1];
    const float* q_vals  = (const float*)d_in[2];
    const int*   d_rows  = (const int*)d_in[3];
    const int*   d_cols  = (const int*)d_in[4];
    const float* d_freqs = (const float*)d_in[5];
    const float* emb     = (const float*)d_in[6];
    const float* W1      = (const float*)d_in[7];
    const float* b1      = (const float*)d_in[8];
    const float* W2      = (const float*)d_in[9];
    const float* b2      = (const float*)d_in[10];
    const float* mu      = (const float*)d_in[11];

    float* rel  = (float*)d_out;          // output 0: rel [256]
    float* dmat = rel + BATCH;            // output 1: d [100001, 256]

    float* colsum2 = (float*)d_ws;        // [2][256]
    float* tdvtab  = colsum2 + 2 * BATCH; // [100001]

    zero_mlp_kernel<<<ZBLK + MBLK, 256, 0, stream>>>(
        (float*)d_out, colsum2, emb, W1, b1, W2, b2, tdvtab);
    scatter_kernel<<<NNZ_D / 512, 256, 0, stream>>>(
        d_rows, d_cols, d_freqs, tdvtab, dmat, colsum2);
    rel_kernel<<<NNZ_Q / 4, 256, 0, stream>>>(
        q_rows, q_cols, q_vals, dmat, colsum2, mu, rel);
}